// Round 1
// baseline (1175.113 us; speedup 1.0000x reference)
//
#include <hip/hip_runtime.h>

// SpikingMultiHeadAttention — B=2, S=2048, D=1024, H=16, hd=64, fp32 I/O.
// Round 6: attn tile stored directly from C-registers (LDS round-trip removed
// from the attn-store path; Ps kept only for the PV transpose), nontemporal
// stores on all streaming outputs (keep K/V L2-resident in attn_mfma),
// s_setprio(1) around MFMA clusters in attn.
//   - spike(scores*scale) == (raw > 0): scale skipped.
//   - Sign chain (Q/K proj, QK^T) in hi/lo bf16 pairs, 3 MFMA passes,
//     accumulation order bit-identical to r4/r5 (absmax must stay 1.75).
// MFMA 16x16x32 bf16 layouts (HW-verified):
//   A-frag: lane holds A[m=lane&15][k=(lane>>4)*8+j], j=0..7
//   B-frag: lane holds Bt[n=lane&15][k=(lane>>4)*8+j]
//   C/D:    lane,reg r -> row m=(lane>>4)*4+r, col n=lane&15

#define SEQ 2048
#define DIM 1024
#define NH 16
#define HD 64
#define BATCH 2
#define MROWS (BATCH * SEQ)   // 4096
#define BHT (BATCH * NH)      // 32

typedef __attribute__((ext_vector_type(8))) short short8;
typedef __attribute__((ext_vector_type(4))) float f4;
typedef unsigned short ushort;

__device__ __forceinline__ f4 mfma16(short8 a, short8 b, f4 c) {
    return __builtin_amdgcn_mfma_f32_16x16x32_bf16(a, b, c, 0, 0, 0);
}
__device__ __forceinline__ ushort rne16(float x) {
    union { float f; unsigned u; } a; a.f = x;
    return (ushort)((a.u + 0x7fffu + ((a.u >> 16) & 1u)) >> 16);
}
// x ~= hi + lo: hi = truncate-to-bf16(x), lo = rne-bf16(x - hi)
__device__ __forceinline__ void split2(float x, ushort& h, ushort& l) {
    union { float f; unsigned u; } a; a.f = x;
    unsigned hu = a.u & 0xffff0000u;
    h = (ushort)(hu >> 16);
    union { unsigned u; float f; } hb; hb.u = hu;
    l = rne16(x - hb.f);
}
__device__ __forceinline__ short8 ld8(const ushort* p) { return *(const short8*)p; }

// ---------- fused weight conversion: 4 jobs on grid.y ----------
__global__ __launch_bounds__(256) void wconv(const float* __restrict__ Wq,
                                             const float* __restrict__ Wk,
                                             const float* __restrict__ Wv,
                                             const float* __restrict__ Wo,
                                             ushort* __restrict__ Wqh, ushort* __restrict__ Wql,
                                             ushort* __restrict__ Wkh, ushort* __restrict__ Wkl,
                                             ushort* __restrict__ Wvb, ushort* __restrict__ Wob) {
    int i = (blockIdx.x * 256 + threadIdx.x) * 4;
    int job = blockIdx.y;
    const float* src = job == 0 ? Wq : job == 1 ? Wk : job == 2 ? Wv : Wo;
    float4 w = *(const float4*)&src[i];
    float xs[4] = {w.x, w.y, w.z, w.w};
    if (job < 2) {
        ushort h[4], l[4];
#pragma unroll
        for (int j = 0; j < 4; ++j) split2(xs[j], h[j], l[j]);
        ushort* ph = job ? Wkh : Wqh;
        ushort* pl = job ? Wkl : Wql;
        *(short4*)&ph[i] = make_short4(h[0], h[1], h[2], h[3]);
        *(short4*)&pl[i] = make_short4(l[0], l[1], l[2], l[3]);
    } else {
        ushort* po = job == 2 ? Wvb : Wob;
        *(short4*)&po[i] = make_short4(rne16(xs[0]), rne16(xs[1]), rne16(xs[2]), rne16(xs[3]));
    }
}

// ---------- fused q/k/v projection (grid.z selects), pipelined loads ----------
template <int B>
__device__ __forceinline__ void ld_qk(const float* __restrict__ X, const ushort* __restrict__ Wh,
                                      const ushort* __restrict__ Wl, int m0, int n0, int la, int qd,
                                      int k0, float4 (&xA)[2][2][2], short8 (&wH)[2][4],
                                      short8 (&wL)[2][4]) {
#pragma unroll
    for (int ms = 0; ms < 2; ++ms) {
        const float* ap = &X[(size_t)(m0 + ms * 16 + la) * DIM + k0 + qd * 8];
        xA[B][ms][0] = *(const float4*)ap;
        xA[B][ms][1] = *(const float4*)(ap + 4);
    }
#pragma unroll
    for (int ns = 0; ns < 4; ++ns) {
        size_t wi = (size_t)(n0 + ns * 16 + la) * DIM + k0 + qd * 8;
        wH[B][ns] = ld8(&Wh[wi]);
        wL[B][ns] = ld8(&Wl[wi]);
    }
}

template <int B>
__device__ __forceinline__ void fma_qk(float4 (&xA)[2][2][2], short8 (&wH)[2][4],
                                       short8 (&wL)[2][4], f4 (&acc)[2][4]) {
    short8 ahi[2], alo[2];
#pragma unroll
    for (int ms = 0; ms < 2; ++ms) {
        float xs[8] = {xA[B][ms][0].x, xA[B][ms][0].y, xA[B][ms][0].z, xA[B][ms][0].w,
                       xA[B][ms][1].x, xA[B][ms][1].y, xA[B][ms][1].z, xA[B][ms][1].w};
#pragma unroll
        for (int j = 0; j < 8; ++j) {
            ushort h, l;
            split2(xs[j], h, l);
            ahi[ms][j] = (short)h;
            alo[ms][j] = (short)l;
        }
    }
#pragma unroll
    for (int ns = 0; ns < 4; ++ns)
#pragma unroll
        for (int ms = 0; ms < 2; ++ms) {
            acc[ms][ns] = mfma16(alo[ms], wH[B][ns], acc[ms][ns]);
            acc[ms][ns] = mfma16(ahi[ms], wL[B][ns], acc[ms][ns]);
            acc[ms][ns] = mfma16(ahi[ms], wH[B][ns], acc[ms][ns]);
        }
}

template <int B>
__device__ __forceinline__ void ld_v(const float* __restrict__ X, const ushort* __restrict__ Wb,
                                     int m0, int n0, int la, int qd, int k0,
                                     float4 (&xA)[2][2][2], short8 (&wH)[2][4]) {
#pragma unroll
    for (int ms = 0; ms < 2; ++ms) {
        const float* ap = &X[(size_t)(m0 + ms * 16 + la) * DIM + k0 + qd * 8];
        xA[B][ms][0] = *(const float4*)ap;
        xA[B][ms][1] = *(const float4*)(ap + 4);
    }
#pragma unroll
    for (int ns = 0; ns < 4; ++ns)
        wH[B][ns] = ld8(&Wb[(size_t)(n0 + ns * 16 + la) * DIM + k0 + qd * 8]);
}

template <int B>
__device__ __forceinline__ void fma_v(float4 (&xA)[2][2][2], short8 (&wH)[2][4], f4 (&acc)[2][4]) {
    short8 a[2];
#pragma unroll
    for (int ms = 0; ms < 2; ++ms) {
        float xs[8] = {xA[B][ms][0].x, xA[B][ms][0].y, xA[B][ms][0].z, xA[B][ms][0].w,
                       xA[B][ms][1].x, xA[B][ms][1].y, xA[B][ms][1].z, xA[B][ms][1].w};
#pragma unroll
        for (int j = 0; j < 8; ++j) a[ms][j] = (short)rne16(xs[j]);
    }
#pragma unroll
    for (int ns = 0; ns < 4; ++ns)
#pragma unroll
        for (int ms = 0; ms < 2; ++ms) acc[ms][ns] = mfma16(a[ms], wH[B][ns], acc[ms][ns]);
}

__global__ __launch_bounds__(256, 2) void proj_qkv(
    const float* __restrict__ query, const float* __restrict__ key, const float* __restrict__ value,
    const ushort* __restrict__ Wqh, const ushort* __restrict__ Wql,
    const ushort* __restrict__ Wkh, const ushort* __restrict__ Wkl,
    const ushort* __restrict__ Wvb,
    const float* __restrict__ bq, const float* __restrict__ bk, const float* __restrict__ bv,
    ushort* __restrict__ Qhi, ushort* __restrict__ Qlo,
    ushort* __restrict__ Khi, ushort* __restrict__ Klo, ushort* __restrict__ Vt) {
    const int z = blockIdx.z;
    const int t = threadIdx.x, wave = t >> 6, lane = t & 63;
    const int la = lane & 15, qd = lane >> 4;
    const int m0 = blockIdx.x * 128 + wave * 32;
    const int n0 = blockIdx.y * 64;

    float4 xA[2][2][2];
    short8 wH[2][4], wL[2][4];
    f4 acc[2][4] = {};

    if (z < 2) {
        const float* X = z ? key : query;
        const ushort* Wh = z ? Wkh : Wqh;
        const ushort* Wl = z ? Wkl : Wql;
        ld_qk<0>(X, Wh, Wl, m0, n0, la, qd, 0, xA, wH, wL);
        for (int k0 = 0; k0 < DIM; k0 += 64) {
            ld_qk<1>(X, Wh, Wl, m0, n0, la, qd, k0 + 32, xA, wH, wL);
            fma_qk<0>(xA, wH, wL, acc);
            ld_qk<0>(X, Wh, Wl, m0, n0, la, qd, (k0 + 64) & (DIM - 1), xA, wH, wL);
            fma_qk<1>(xA, wH, wL, acc);
        }
        const float* bias = z ? bk : bq;
        ushort* Oh = z ? Khi : Qhi;
        ushort* Ol = z ? Klo : Qlo;
#pragma unroll
        for (int ns = 0; ns < 4; ++ns) {
            int n = n0 + ns * 16 + la;
            float bvv = bias[n];
            int h = n >> 6, d = n & 63;
#pragma unroll
            for (int ms = 0; ms < 2; ++ms)
#pragma unroll
                for (int r = 0; r < 4; ++r) {
                    int m = m0 + ms * 16 + qd * 4 + r;
                    int b = m >> 11, s = m & 2047;
                    ushort hh, ll;
                    split2(acc[ms][ns][r] + bvv, hh, ll);
                    size_t o = ((size_t)(b * NH + h) * SEQ + s) * HD + d;
                    __builtin_nontemporal_store(hh, &Oh[o]);
                    __builtin_nontemporal_store(ll, &Ol[o]);
                }
        }
    } else {
        __shared__ ushort Ts[4][64][40];  // per-wave private [wave][d][m], 16B-aligned rows
        ld_v<0>(value, Wvb, m0, n0, la, qd, 0, xA, wH);
        for (int k0 = 0; k0 < DIM; k0 += 64) {
            ld_v<1>(value, Wvb, m0, n0, la, qd, k0 + 32, xA, wH);
            fma_v<0>(xA, wH, acc);
            ld_v<0>(value, Wvb, m0, n0, la, qd, (k0 + 64) & (DIM - 1), xA, wH);
            fma_v<1>(xA, wH, acc);
        }
#pragma unroll
        for (int ns = 0; ns < 4; ++ns) {
            float bvv = bv[n0 + ns * 16 + la];
#pragma unroll
            for (int ms = 0; ms < 2; ++ms)
#pragma unroll
                for (int r = 0; r < 4; ++r)
                    Ts[wave][ns * 16 + la][ms * 16 + qd * 4 + r] = rne16(acc[ms][ns][r] + bvv);
        }
        // same-wave LDS round-trip (lgkmcnt-ordered, wave-private region)
        int b = m0 >> 11, s0 = m0 & 2047, h = n0 >> 6;
        size_t vbase = (size_t)(b * NH + h) * HD * SEQ;
#pragma unroll
        for (int it = 0; it < 4; ++it) {
            int d = it * 16 + (lane >> 2), sc = (lane & 3) * 8;
            short8 v0 = *(const short8*)&Ts[wave][d][sc];
            __builtin_nontemporal_store(v0, (short8*)&Vt[vbase + (size_t)d * SEQ + s0 + sc]);
        }
    }
}

// ---------- fused attention, 32-col half-tiles, pipelined loads ----------
template <int B>
__device__ __forceinline__ void ld_at(const ushort* __restrict__ Khi, const ushort* __restrict__ Klo,
                                      const ushort* __restrict__ Vt, int bh, int c0, int la, int qd,
                                      short8 (&kH)[2][2][2], short8 (&kL)[2][2][2],
                                      short8 (&vB)[2][4]) {
#pragma unroll
    for (int n2 = 0; n2 < 2; ++n2)
#pragma unroll
        for (int ks = 0; ks < 2; ++ks) {
            size_t ki = ((size_t)bh * SEQ + c0 + n2 * 16 + la) * HD + ks * 32 + qd * 8;
            kH[B][n2][ks] = ld8(&Khi[ki]);
            kL[B][n2][ks] = ld8(&Klo[ki]);
        }
#pragma unroll
    for (int ns = 0; ns < 4; ++ns)
        vB[B][ns] = ld8(&Vt[((size_t)bh * HD + ns * 16 + la) * SEQ + c0 + qd * 8]);
}

template <int B>
__device__ __forceinline__ void half_at(ushort (*Ps)[40], float* __restrict__ attn,
                                        int bh, int q0, int c0, int wave, int la, int qd,
                                        short8 (&qhi)[2][2], short8 (&qlo)[2][2],
                                        short8 (&kH)[2][2][2], short8 (&kL)[2][2][2],
                                        short8 (&vB)[2][4], f4 (&cacc)[2][4]) {
    f4 s[2][2] = {};
    __builtin_amdgcn_s_setprio(1);
#pragma unroll
    for (int n2 = 0; n2 < 2; ++n2)
#pragma unroll
        for (int ks = 0; ks < 2; ++ks)
#pragma unroll
            for (int ms = 0; ms < 2; ++ms) {
                s[ms][n2] = mfma16(qlo[ms][ks], kH[B][n2][ks], s[ms][n2]);
                s[ms][n2] = mfma16(qhi[ms][ks], kL[B][n2][ks], s[ms][n2]);
                s[ms][n2] = mfma16(qhi[ms][ks], kH[B][n2][ks], s[ms][n2]);
            }
    __builtin_amdgcn_s_setprio(0);
    // spike -> Ps (wave-private rows): kept ONLY for the PV A-fragment transpose
#pragma unroll
    for (int ms = 0; ms < 2; ++ms)
#pragma unroll
        for (int n2 = 0; n2 < 2; ++n2)
#pragma unroll
            for (int r = 0; r < 4; ++r)
                Ps[wave * 32 + ms * 16 + qd * 4 + r][n2 * 16 + la] =
                    s[ms][n2][r] > 0.f ? (ushort)0x3f80 : (ushort)0;
    // attn tile: store straight from C-regs (64B segments, nontemporal — keep
    // the 512 MiB stream out of L2 so K/V tiles stay resident)
#pragma unroll
    for (int ms = 0; ms < 2; ++ms)
#pragma unroll
        for (int n2 = 0; n2 < 2; ++n2)
#pragma unroll
            for (int r = 0; r < 4; ++r) {
                int row = ms * 16 + qd * 4 + r;
                __builtin_nontemporal_store(
                    s[ms][n2][r] > 0.f ? 1.0f : 0.0f,
                    &attn[((size_t)bh * SEQ + q0 + row) * SEQ + c0 + n2 * 16 + la]);
            }
    // ctx += P @ V over this 32-col half (same-wave LDS readback, lgkmcnt-ordered)
    short8 pa[2];
#pragma unroll
    for (int ms = 0; ms < 2; ++ms)
        pa[ms] = *(const short8*)&Ps[wave * 32 + ms * 16 + la][qd * 8];
    __builtin_amdgcn_s_setprio(1);
#pragma unroll
    for (int ns = 0; ns < 4; ++ns)
#pragma unroll
        for (int ms = 0; ms < 2; ++ms) cacc[ms][ns] = mfma16(pa[ms], vB[B][ns], cacc[ms][ns]);
    __builtin_amdgcn_s_setprio(0);
}

__global__ __launch_bounds__(256, 2) void attn_mfma(
    const ushort* __restrict__ Qhi, const ushort* __restrict__ Qlo,
    const ushort* __restrict__ Khi, const ushort* __restrict__ Klo,
    const ushort* __restrict__ Vt, float* __restrict__ attn, ushort* __restrict__ ctxb) {
    __shared__ ushort Ps[128][40];
    const int t = threadIdx.x, wave = t >> 6, lane = t & 63;
    const int la = lane & 15, qd = lane >> 4;
    const int bh = blockIdx.x;
    const int q0 = blockIdx.y * 128 + wave * 32;

    short8 qhi[2][2], qlo[2][2];
#pragma unroll
    for (int ms = 0; ms < 2; ++ms)
#pragma unroll
        for (int ks = 0; ks < 2; ++ks) {
            size_t qi = ((size_t)bh * SEQ + q0 + ms * 16 + la) * HD + ks * 32 + qd * 8;
            qhi[ms][ks] = ld8(&Qhi[qi]);
            qlo[ms][ks] = ld8(&Qlo[qi]);
        }

    short8 kH[2][2][2], kL[2][2][2], vB[2][4];
    f4 cacc[2][4] = {};
    ld_at<0>(Khi, Klo, Vt, bh, 0, la, qd, kH, kL, vB);
    for (int h = 0; h < 64; h += 2) {
        ld_at<1>(Khi, Klo, Vt, bh, (h + 1) * 32, la, qd, kH, kL, vB);
        half_at<0>(Ps, attn, bh, q0, h * 32, wave, la, qd, qhi, qlo, kH, kL, vB, cacc);
        ld_at<0>(Khi, Klo, Vt, bh, ((h + 2) & 63) * 32, la, qd, kH, kL, vB);
        half_at<1>(Ps, attn, bh, q0, (h + 1) * 32, wave, la, qd, qhi, qlo, kH, kL, vB, cacc);
    }
#pragma unroll
    for (int ns = 0; ns < 4; ++ns)
#pragma unroll
        for (int ms = 0; ms < 2; ++ms)
#pragma unroll
            for (int r = 0; r < 4; ++r) {
                int qrow = q0 + ms * 16 + qd * 4 + r;
                __builtin_nontemporal_store(
                    rne16(cacc[ms][ns][r]),
                    &ctxb[((size_t)bh * SEQ + qrow) * HD + ns * 16 + la]);
            }
}

// ---------- out projection, pipelined ----------
template <int B>
__device__ __forceinline__ void ld_o(const ushort* __restrict__ Ctx, const ushort* __restrict__ Wb,
                                     int m0, int n0, int la, int qd, int k0,
                                     short8 (&aO)[2][2], short8 (&wO)[2][4]) {
#pragma unroll
    for (int ms = 0; ms < 2; ++ms) {
        int m = m0 + ms * 16 + la;
        int b = m >> 11, s = m & 2047;
        int k = k0 + qd * 8;
        int h = k >> 6, d = k & 63;
        aO[B][ms] = ld8(&Ctx[((size_t)(b * NH + h) * SEQ + s) * HD + d]);
    }
#pragma unroll
    for (int ns = 0; ns < 4; ++ns)
        wO[B][ns] = ld8(&Wb[(size_t)(n0 + ns * 16 + la) * DIM + k0 + qd * 8]);
}

__global__ __launch_bounds__(256, 2) void proj_out(const ushort* __restrict__ Ctx,
                                                   const ushort* __restrict__ Wb,
                                                   const float* __restrict__ bias,
                                                   float* __restrict__ out) {
    const int t = threadIdx.x, wave = t >> 6, lane = t & 63;
    const int la = lane & 15, qd = lane >> 4;
    const int m0 = blockIdx.x * 128 + wave * 32;
    const int n0 = blockIdx.y * 64;

    short8 aO[2][2], wO[2][4];
    f4 acc[2][4] = {};
    ld_o<0>(Ctx, Wb, m0, n0, la, qd, 0, aO, wO);
    for (int k0 = 0; k0 < DIM; k0 += 64) {
        ld_o<1>(Ctx, Wb, m0, n0, la, qd, k0 + 32, aO, wO);
#pragma unroll
        for (int ns = 0; ns < 4; ++ns)
#pragma unroll
            for (int ms = 0; ms < 2; ++ms) acc[ms][ns] = mfma16(aO[0][ms], wO[0][ns], acc[ms][ns]);
        ld_o<0>(Ctx, Wb, m0, n0, la, qd, (k0 + 64) & (DIM - 1), aO, wO);
#pragma unroll
        for (int ns = 0; ns < 4; ++ns)
#pragma unroll
            for (int ms = 0; ms < 2; ++ms) acc[ms][ns] = mfma16(aO[1][ms], wO[1][ns], acc[ms][ns]);
    }
#pragma unroll
    for (int ns = 0; ns < 4; ++ns) {
        int n = n0 + ns * 16 + la;
        float bvv = bias[n];
#pragma unroll
        for (int ms = 0; ms < 2; ++ms)
#pragma unroll
            for (int r = 0; r < 4; ++r) {
                int m = m0 + ms * 16 + qd * 4 + r;
                __builtin_nontemporal_store(acc[ms][ns][r] + bvv, &out[(size_t)m * DIM + n]);
            }
    }
}

extern "C" void kernel_launch(void* const* d_in, const int* in_sizes, int n_in,
                              void* d_out, int out_size, void* d_ws, size_t ws_size,
                              hipStream_t stream) {
    const float* query = (const float*)d_in[0];
    const float* key   = (const float*)d_in[1];
    const float* value = (const float*)d_in[2];
    const float* Wq = (const float*)d_in[3];
    const float* bq = (const float*)d_in[4];
    const float* Wk = (const float*)d_in[5];
    const float* bk = (const float*)d_in[6];
    const float* Wv = (const float*)d_in[7];
    const float* bv = (const float*)d_in[8];
    const float* Wo = (const float*)d_in[9];
    const float* bo = (const float*)d_in[10];

    float* out  = (float*)d_out;
    float* attn = out + (size_t)MROWS * DIM;

    const size_t NE = (size_t)MROWS * DIM;  // 4,194,304
    const size_t WE = (size_t)DIM * DIM;    // 1,048,576
    ushort* Qhi = (ushort*)d_ws;            // 5 x NE = 40 MiB
    ushort* Qlo = Qhi + NE;
    ushort* Khi = Qlo + NE;
    ushort* Klo = Khi + NE;
    ushort* Vt  = Klo + NE;
    ushort* Wqh = Vt + NE;                  // 6 x WE = 12 MiB
    ushort* Wql = Wqh + WE;
    ushort* Wkh = Wql + WE;
    ushort* Wkl = Wkh + WE;
    ushort* Wvb = Wkl + WE;
    ushort* Wob = Wvb + WE;
    ushort* Ctx = Wqh;                      // overlays Wqh..Wkl (dead after proj_qkv)

    dim3 blk(256);
    hipLaunchKernelGGL(wconv, dim3(WE / 1024, 4), blk, 0, stream,
                       Wq, Wk, Wv, Wo, Wqh, Wql, Wkh, Wkl, Wvb, Wob);
    hipLaunchKernelGGL(proj_qkv, dim3(32, 16, 3), blk, 0, stream,
                       query, key, value, Wqh, Wql, Wkh, Wkl, Wvb, bq, bk, bv,
                       Qhi, Qlo, Khi, Klo, Vt);
    hipLaunchKernelGGL(attn_mfma, dim3(32, 16), blk, 0, stream,
                       Qhi, Qlo, Khi, Klo, Vt, attn, Ctx);
    hipLaunchKernelGGL(proj_out, dim3(32, 16), blk, 0, stream, Ctx, Wob, bo, out);
}

// Round 4
// 1164.221 us; speedup vs baseline: 1.0094x; 1.0094x over previous
//
#include <hip/hip_runtime.h>

// SpikingMultiHeadAttention — B=2, S=2048, D=1024, H=16, hd=64, fp32 I/O.
// Round 7c: identical to r7b (infra failure, never ran).
// attn_mfma occupancy restructure: 16 q-rows/wave, grid 32x32 = 4 blocks/CU,
// launch_bounds(256,4), single-buffered K/V regs, r5-style LDS-readback attn
// store path with ext_vector f4 nontemporal stores.
//   - spike(scores*scale) == (raw > 0): scale skipped.
//   - Sign chain (Q/K proj, QK^T) in hi/lo bf16 pairs, 3 MFMA passes,
//     per-element accumulation order bit-identical to r5 (absmax 1.75).
// MFMA 16x16x32 bf16 layouts (HW-verified):
//   A-frag: lane holds A[m=lane&15][k=(lane>>4)*8+j], j=0..7
//   B-frag: lane holds Bt[n=lane&15][k=(lane>>4)*8+j]
//   C/D:    lane,reg r -> row m=(lane>>4)*4+r, col n=lane&15

#define SEQ 2048
#define DIM 1024
#define NH 16
#define HD 64
#define BATCH 2
#define MROWS (BATCH * SEQ)   // 4096
#define BHT (BATCH * NH)      // 32

typedef __attribute__((ext_vector_type(8))) short short8;
typedef __attribute__((ext_vector_type(4))) float f4;
typedef unsigned short ushort;

__device__ __forceinline__ f4 mfma16(short8 a, short8 b, f4 c) {
    return __builtin_amdgcn_mfma_f32_16x16x32_bf16(a, b, c, 0, 0, 0);
}
__device__ __forceinline__ ushort rne16(float x) {
    union { float f; unsigned u; } a; a.f = x;
    return (ushort)((a.u + 0x7fffu + ((a.u >> 16) & 1u)) >> 16);
}
// x ~= hi + lo: hi = truncate-to-bf16(x), lo = rne-bf16(x - hi)
__device__ __forceinline__ void split2(float x, ushort& h, ushort& l) {
    union { float f; unsigned u; } a; a.f = x;
    unsigned hu = a.u & 0xffff0000u;
    h = (ushort)(hu >> 16);
    union { unsigned u; float f; } hb; hb.u = hu;
    l = rne16(x - hb.f);
}
__device__ __forceinline__ short8 ld8(const ushort* p) { return *(const short8*)p; }

// ---------- fused weight conversion: 4 jobs on grid.y ----------
__global__ __launch_bounds__(256) void wconv(const float* __restrict__ Wq,
                                             const float* __restrict__ Wk,
                                             const float* __restrict__ Wv,
                                             const float* __restrict__ Wo,
                                             ushort* __restrict__ Wqh, ushort* __restrict__ Wql,
                                             ushort* __restrict__ Wkh, ushort* __restrict__ Wkl,
                                             ushort* __restrict__ Wvb, ushort* __restrict__ Wob) {
    int i = (blockIdx.x * 256 + threadIdx.x) * 4;
    int job = blockIdx.y;
    const float* src = job == 0 ? Wq : job == 1 ? Wk : job == 2 ? Wv : Wo;
    float4 w = *(const float4*)&src[i];
    float xs[4] = {w.x, w.y, w.z, w.w};
    if (job < 2) {
        ushort h[4], l[4];
#pragma unroll
        for (int j = 0; j < 4; ++j) split2(xs[j], h[j], l[j]);
        ushort* ph = job ? Wkh : Wqh;
        ushort* pl = job ? Wkl : Wql;
        *(short4*)&ph[i] = make_short4(h[0], h[1], h[2], h[3]);
        *(short4*)&pl[i] = make_short4(l[0], l[1], l[2], l[3]);
    } else {
        ushort* po = job == 2 ? Wvb : Wob;
        *(short4*)&po[i] = make_short4(rne16(xs[0]), rne16(xs[1]), rne16(xs[2]), rne16(xs[3]));
    }
}

// ---------- fused q/k/v projection (grid.z selects), pipelined loads ----------
template <int B>
__device__ __forceinline__ void ld_qk(const float* __restrict__ X, const ushort* __restrict__ Wh,
                                      const ushort* __restrict__ Wl, int m0, int n0, int la, int qd,
                                      int k0, float4 (&xA)[2][2][2], short8 (&wH)[2][4],
                                      short8 (&wL)[2][4]) {
#pragma unroll
    for (int ms = 0; ms < 2; ++ms) {
        const float* ap = &X[(size_t)(m0 + ms * 16 + la) * DIM + k0 + qd * 8];
        xA[B][ms][0] = *(const float4*)ap;
        xA[B][ms][1] = *(const float4*)(ap + 4);
    }
#pragma unroll
    for (int ns = 0; ns < 4; ++ns) {
        size_t wi = (size_t)(n0 + ns * 16 + la) * DIM + k0 + qd * 8;
        wH[B][ns] = ld8(&Wh[wi]);
        wL[B][ns] = ld8(&Wl[wi]);
    }
}

template <int B>
__device__ __forceinline__ void fma_qk(float4 (&xA)[2][2][2], short8 (&wH)[2][4],
                                       short8 (&wL)[2][4], f4 (&acc)[2][4]) {
    short8 ahi[2], alo[2];
#pragma unroll
    for (int ms = 0; ms < 2; ++ms) {
        float xs[8] = {xA[B][ms][0].x, xA[B][ms][0].y, xA[B][ms][0].z, xA[B][ms][0].w,
                       xA[B][ms][1].x, xA[B][ms][1].y, xA[B][ms][1].z, xA[B][ms][1].w};
#pragma unroll
        for (int j = 0; j < 8; ++j) {
            ushort h, l;
            split2(xs[j], h, l);
            ahi[ms][j] = (short)h;
            alo[ms][j] = (short)l;
        }
    }
#pragma unroll
    for (int ns = 0; ns < 4; ++ns)
#pragma unroll
        for (int ms = 0; ms < 2; ++ms) {
            acc[ms][ns] = mfma16(alo[ms], wH[B][ns], acc[ms][ns]);
            acc[ms][ns] = mfma16(ahi[ms], wL[B][ns], acc[ms][ns]);
            acc[ms][ns] = mfma16(ahi[ms], wH[B][ns], acc[ms][ns]);
        }
}

template <int B>
__device__ __forceinline__ void ld_v(const float* __restrict__ X, const ushort* __restrict__ Wb,
                                     int m0, int n0, int la, int qd, int k0,
                                     float4 (&xA)[2][2][2], short8 (&wH)[2][4]) {
#pragma unroll
    for (int ms = 0; ms < 2; ++ms) {
        const float* ap = &X[(size_t)(m0 + ms * 16 + la) * DIM + k0 + qd * 8];
        xA[B][ms][0] = *(const float4*)ap;
        xA[B][ms][1] = *(const float4*)(ap + 4);
    }
#pragma unroll
    for (int ns = 0; ns < 4; ++ns)
        wH[B][ns] = ld8(&Wb[(size_t)(n0 + ns * 16 + la) * DIM + k0 + qd * 8]);
}

template <int B>
__device__ __forceinline__ void fma_v(float4 (&xA)[2][2][2], short8 (&wH)[2][4], f4 (&acc)[2][4]) {
    short8 a[2];
#pragma unroll
    for (int ms = 0; ms < 2; ++ms) {
        float xs[8] = {xA[B][ms][0].x, xA[B][ms][0].y, xA[B][ms][0].z, xA[B][ms][0].w,
                       xA[B][ms][1].x, xA[B][ms][1].y, xA[B][ms][1].z, xA[B][ms][1].w};
#pragma unroll
        for (int j = 0; j < 8; ++j) a[ms][j] = (short)rne16(xs[j]);
    }
#pragma unroll
    for (int ns = 0; ns < 4; ++ns)
#pragma unroll
        for (int ms = 0; ms < 2; ++ms) acc[ms][ns] = mfma16(a[ms], wH[B][ns], acc[ms][ns]);
}

__global__ __launch_bounds__(256, 2) void proj_qkv(
    const float* __restrict__ query, const float* __restrict__ key, const float* __restrict__ value,
    const ushort* __restrict__ Wqh, const ushort* __restrict__ Wql,
    const ushort* __restrict__ Wkh, const ushort* __restrict__ Wkl,
    const ushort* __restrict__ Wvb,
    const float* __restrict__ bq, const float* __restrict__ bk, const float* __restrict__ bv,
    ushort* __restrict__ Qhi, ushort* __restrict__ Qlo,
    ushort* __restrict__ Khi, ushort* __restrict__ Klo, ushort* __restrict__ Vt) {
    const int z = blockIdx.z;
    const int t = threadIdx.x, wave = t >> 6, lane = t & 63;
    const int la = lane & 15, qd = lane >> 4;
    const int m0 = blockIdx.x * 128 + wave * 32;
    const int n0 = blockIdx.y * 64;

    float4 xA[2][2][2];
    short8 wH[2][4], wL[2][4];
    f4 acc[2][4] = {};

    if (z < 2) {
        const float* X = z ? key : query;
        const ushort* Wh = z ? Wkh : Wqh;
        const ushort* Wl = z ? Wkl : Wql;
        ld_qk<0>(X, Wh, Wl, m0, n0, la, qd, 0, xA, wH, wL);
        for (int k0 = 0; k0 < DIM; k0 += 64) {
            ld_qk<1>(X, Wh, Wl, m0, n0, la, qd, k0 + 32, xA, wH, wL);
            fma_qk<0>(xA, wH, wL, acc);
            ld_qk<0>(X, Wh, Wl, m0, n0, la, qd, (k0 + 64) & (DIM - 1), xA, wH, wL);
            fma_qk<1>(xA, wH, wL, acc);
        }
        const float* bias = z ? bk : bq;
        ushort* Oh = z ? Khi : Qhi;
        ushort* Ol = z ? Klo : Qlo;
#pragma unroll
        for (int ns = 0; ns < 4; ++ns) {
            int n = n0 + ns * 16 + la;
            float bvv = bias[n];
            int h = n >> 6, d = n & 63;
#pragma unroll
            for (int ms = 0; ms < 2; ++ms)
#pragma unroll
                for (int r = 0; r < 4; ++r) {
                    int m = m0 + ms * 16 + qd * 4 + r;
                    int b = m >> 11, s = m & 2047;
                    ushort hh, ll;
                    split2(acc[ms][ns][r] + bvv, hh, ll);
                    size_t o = ((size_t)(b * NH + h) * SEQ + s) * HD + d;
                    __builtin_nontemporal_store(hh, &Oh[o]);
                    __builtin_nontemporal_store(ll, &Ol[o]);
                }
        }
    } else {
        __shared__ ushort Ts[4][64][40];  // per-wave private [wave][d][m], 16B-aligned rows
        ld_v<0>(value, Wvb, m0, n0, la, qd, 0, xA, wH);
        for (int k0 = 0; k0 < DIM; k0 += 64) {
            ld_v<1>(value, Wvb, m0, n0, la, qd, k0 + 32, xA, wH);
            fma_v<0>(xA, wH, acc);
            ld_v<0>(value, Wvb, m0, n0, la, qd, (k0 + 64) & (DIM - 1), xA, wH);
            fma_v<1>(xA, wH, acc);
        }
#pragma unroll
        for (int ns = 0; ns < 4; ++ns) {
            float bvv = bv[n0 + ns * 16 + la];
#pragma unroll
            for (int ms = 0; ms < 2; ++ms)
#pragma unroll
                for (int r = 0; r < 4; ++r)
                    Ts[wave][ns * 16 + la][ms * 16 + qd * 4 + r] = rne16(acc[ms][ns][r] + bvv);
        }
        // same-wave LDS round-trip (lgkmcnt-ordered, wave-private region)
        int b = m0 >> 11, s0 = m0 & 2047, h = n0 >> 6;
        size_t vbase = (size_t)(b * NH + h) * HD * SEQ;
#pragma unroll
        for (int it = 0; it < 4; ++it) {
            int d = it * 16 + (lane >> 2), sc = (lane & 3) * 8;
            short8 v0 = *(const short8*)&Ts[wave][d][sc];
            __builtin_nontemporal_store(v0, (short8*)&Vt[vbase + (size_t)d * SEQ + s0 + sc]);
        }
    }
}

// ---------- fused attention: 16 q-rows/wave, 32-key half-tiles ----------
// Grid 32 (bh) x 32 (q-blocks of 64) -> 1024 blocks = 4 blocks/CU.
__global__ __launch_bounds__(256, 4) void attn_mfma(
    const ushort* __restrict__ Qhi, const ushort* __restrict__ Qlo,
    const ushort* __restrict__ Khi, const ushort* __restrict__ Klo,
    const ushort* __restrict__ Vt, float* __restrict__ attn, ushort* __restrict__ ctxb) {
    __shared__ ushort Ps[64][40];  // 4 waves x 16 wave-private rows, 16B-aligned pitch
    const int t = threadIdx.x, wave = t >> 6, lane = t & 63;
    const int la = lane & 15, qd = lane >> 4;
    const int bh = blockIdx.x;
    const int q0 = blockIdx.y * 64 + wave * 16;

    short8 qhi[2], qlo[2];
#pragma unroll
    for (int ks = 0; ks < 2; ++ks) {
        size_t qi = ((size_t)bh * SEQ + q0 + la) * HD + ks * 32 + qd * 8;
        qhi[ks] = ld8(&Qhi[qi]);
        qlo[ks] = ld8(&Qlo[qi]);
    }

    f4 cacc[4] = {};
    for (int h = 0; h < 64; ++h) {
        const int c0 = h * 32;
        // K/V loads: L2-resident (~1.5 MiB/bh working set); latency hidden by
        // 4 waves/SIMD TLP instead of register double-buffering (VGPR budget).
        short8 kH[2][2], kL[2][2], vB[4];
#pragma unroll
        for (int n2 = 0; n2 < 2; ++n2)
#pragma unroll
            for (int ks = 0; ks < 2; ++ks) {
                size_t ki = ((size_t)bh * SEQ + c0 + n2 * 16 + la) * HD + ks * 32 + qd * 8;
                kH[n2][ks] = ld8(&Khi[ki]);
                kL[n2][ks] = ld8(&Klo[ki]);
            }
#pragma unroll
        for (int ns = 0; ns < 4; ++ns)
            vB[ns] = ld8(&Vt[((size_t)bh * HD + ns * 16 + la) * SEQ + c0 + qd * 8]);

        // QK^T, 3-pass hi/lo chain — per-element op order identical to r5
        f4 s[2] = {};
        __builtin_amdgcn_s_setprio(1);
#pragma unroll
        for (int n2 = 0; n2 < 2; ++n2)
#pragma unroll
            for (int ks = 0; ks < 2; ++ks) {
                s[n2] = mfma16(qlo[ks], kH[n2][ks], s[n2]);
                s[n2] = mfma16(qhi[ks], kL[n2][ks], s[n2]);
                s[n2] = mfma16(qhi[ks], kH[n2][ks], s[n2]);
            }
        __builtin_amdgcn_s_setprio(0);

        // spike -> Ps (wave-private rows)
#pragma unroll
        for (int n2 = 0; n2 < 2; ++n2)
#pragma unroll
            for (int r = 0; r < 4; ++r)
                Ps[wave * 16 + qd * 4 + r][n2 * 16 + la] =
                    s[n2][r] > 0.f ? (ushort)0x3f80 : (ushort)0;

        // attn tile: Ps readback -> widen -> coalesced float4 nt stores
        // (same-wave rows, lgkmcnt-ordered; ext_vector f4 for the builtin)
#pragma unroll
        for (int it = 0; it < 2; ++it) {
            int row = it * 8 + (lane >> 3);
            short4 p = *(const short4*)&Ps[wave * 16 + row][(lane & 7) * 4];
            f4 o;
            o.x = __uint_as_float(((unsigned)(ushort)p.x) << 16);
            o.y = __uint_as_float(((unsigned)(ushort)p.y) << 16);
            o.z = __uint_as_float(((unsigned)(ushort)p.z) << 16);
            o.w = __uint_as_float(((unsigned)(ushort)p.w) << 16);
            __builtin_nontemporal_store(
                o, (f4*)&attn[((size_t)bh * SEQ + q0 + row) * SEQ + c0 + (lane & 7) * 4]);
        }

        // ctx += P @ V over this 32-key half
        short8 pa = *(const short8*)&Ps[wave * 16 + la][qd * 8];
        __builtin_amdgcn_s_setprio(1);
#pragma unroll
        for (int ns = 0; ns < 4; ++ns) cacc[ns] = mfma16(pa, vB[ns], cacc[ns]);
        __builtin_amdgcn_s_setprio(0);
    }
#pragma unroll
    for (int ns = 0; ns < 4; ++ns)
#pragma unroll
        for (int r = 0; r < 4; ++r) {
            int qrow = q0 + qd * 4 + r;
            __builtin_nontemporal_store(rne16(cacc[ns][r]),
                                        &ctxb[((size_t)bh * SEQ + qrow) * HD + ns * 16 + la]);
        }
}

// ---------- out projection, pipelined ----------
template <int B>
__device__ __forceinline__ void ld_o(const ushort* __restrict__ Ctx, const ushort* __restrict__ Wb,
                                     int m0, int n0, int la, int qd, int k0,
                                     short8 (&aO)[2][2], short8 (&wO)[2][4]) {
#pragma unroll
    for (int ms = 0; ms < 2; ++ms) {
        int m = m0 + ms * 16 + la;
        int b = m >> 11, s = m & 2047;
        int k = k0 + qd * 8;
        int h = k >> 6, d = k & 63;
        aO[B][ms] = ld8(&Ctx[((size_t)(b * NH + h) * SEQ + s) * HD + d]);
    }
#pragma unroll
    for (int ns = 0; ns < 4; ++ns)
        wO[B][ns] = ld8(&Wb[(size_t)(n0 + ns * 16 + la) * DIM + k0 + qd * 8]);
}

__global__ __launch_bounds__(256, 2) void proj_out(const ushort* __restrict__ Ctx,
                                                   const ushort* __restrict__ Wb,
                                                   const float* __restrict__ bias,
                                                   float* __restrict__ out) {
    const int t = threadIdx.x, wave = t >> 6, lane = t & 63;
    const int la = lane & 15, qd = lane >> 4;
    const int m0 = blockIdx.x * 128 + wave * 32;
    const int n0 = blockIdx.y * 64;

    short8 aO[2][2], wO[2][4];
    f4 acc[2][4] = {};
    ld_o<0>(Ctx, Wb, m0, n0, la, qd, 0, aO, wO);
    for (int k0 = 0; k0 < DIM; k0 += 64) {
        ld_o<1>(Ctx, Wb, m0, n0, la, qd, k0 + 32, aO, wO);
#pragma unroll
        for (int ns = 0; ns < 4; ++ns)
#pragma unroll
            for (int ms = 0; ms < 2; ++ms) acc[ms][ns] = mfma16(aO[0][ms], wO[0][ns], acc[ms][ns]);
        ld_o<0>(Ctx, Wb, m0, n0, la, qd, (k0 + 64) & (DIM - 1), aO, wO);
#pragma unroll
        for (int ns = 0; ns < 4; ++ns)
#pragma unroll
            for (int ms = 0; ms < 2; ++ms) acc[ms][ns] = mfma16(aO[1][ms], wO[1][ns], acc[ms][ns]);
    }
#pragma unroll
    for (int ns = 0; ns < 4; ++ns) {
        int n = n0 + ns * 16 + la;
        float bvv = bias[n];
#pragma unroll
        for (int ms = 0; ms < 2; ++ms)
#pragma unroll
            for (int r = 0; r < 4; ++r) {
                int m = m0 + ms * 16 + qd * 4 + r;
                __builtin_nontemporal_store(acc[ms][ns][r] + bvv, &out[(size_t)m * DIM + n]);
            }
    }
}

extern "C" void kernel_launch(void* const* d_in, const int* in_sizes, int n_in,
                              void* d_out, int out_size, void* d_ws, size_t ws_size,
                              hipStream_t stream) {
    const float* query = (const float*)d_in[0];
    const float* key   = (const float*)d_in[1];
    const float* value = (const float*)d_in[2];
    const float* Wq = (const float*)d_in[3];
    const float* bq = (const float*)d_in[4];
    const float* Wk = (const float*)d_in[5];
    const float* bk = (const float*)d_in[6];
    const float* Wv = (const float*)d_in[7];
    const float* bv = (const float*)d_in[8];
    const float* Wo = (const float*)d_in[9];
    const float* bo = (const float*)d_in[10];

    float* out  = (float*)d_out;
    float* attn = out + (size_t)MROWS * DIM;

    const size_t NE = (size_t)MROWS * DIM;  // 4,194,304
    const size_t WE = (size_t)DIM * DIM;    // 1,048,576
    ushort* Qhi = (ushort*)d_ws;            // 5 x NE = 40 MiB
    ushort* Qlo = Qhi + NE;
    ushort* Khi = Qlo + NE;
    ushort* Klo = Khi + NE;
    ushort* Vt  = Klo + NE;
    ushort* Wqh = Vt + NE;                  // 6 x WE = 12 MiB
    ushort* Wql = Wqh + WE;
    ushort* Wkh = Wql + WE;
    ushort* Wkl = Wkh + WE;
    ushort* Wvb = Wkl + WE;
    ushort* Wob = Wvb + WE;
    ushort* Ctx = Wqh;                      // overlays Wqh..Wkl (dead after proj_qkv)

    dim3 blk(256);
    hipLaunchKernelGGL(wconv, dim3(WE / 1024, 4), blk, 0, stream,
                       Wq, Wk, Wv, Wo, Wqh, Wql, Wkh, Wkl, Wvb, Wob);
    hipLaunchKernelGGL(proj_qkv, dim3(32, 16, 3), blk, 0, stream,
                       query, key, value, Wqh, Wql, Wkh, Wkl, Wvb, bq, bk, bv,
                       Qhi, Qlo, Khi, Klo, Vt);
    hipLaunchKernelGGL(attn_mfma, dim3(32, 32), blk, 0, stream,
                       Qhi, Qlo, Khi, Klo, Vt, attn, Ctx);
    hipLaunchKernelGGL(proj_out, dim3(32, 16), blk, 0, stream, Ctx, Wob, bo, out);
}

// Round 5
// 1021.204 us; speedup vs baseline: 1.1507x; 1.1400x over previous
//
#include <hip/hip_runtime.h>

// SpikingMultiHeadAttention — B=2, S=2048, D=1024, H=16, hd=64, fp32 I/O.
// Round 8: attn_mfma gets LDS-staged K (hi+lo), double-buffered, shared by
// all 4 waves of the block (they share bh -> identical K). Staging uses
// global_load_lds width=16 with PRE-SWIZZLED global source (linear LDS dest,
// XOR-involution chunk swizzle applied again on the ds_read side) so the
// stride-128B B-fragment reads are ~2-way instead of 16-way bank conflicts.
// One __syncthreads per 32-key tile; tile t+1 staged async during tile t.
// V stays register-loaded (L2-resident). Compute/numerics bit-identical to
// r7 (same bf16 words, same MFMA order) -> absmax must stay 1.75.
// MFMA 16x16x32 bf16 layouts (HW-verified):
//   A-frag: lane holds A[m=lane&15][k=(lane>>4)*8+j], j=0..7
//   B-frag: lane holds Bt[n=lane&15][k=(lane>>4)*8+j]
//   C/D:    lane,reg r -> row m=(lane>>4)*4+r, col n=lane&15

#define SEQ 2048
#define DIM 1024
#define NH 16
#define HD 64
#define BATCH 2
#define MROWS (BATCH * SEQ)   // 4096
#define BHT (BATCH * NH)      // 32

typedef __attribute__((ext_vector_type(8))) short short8;
typedef __attribute__((ext_vector_type(4))) float f4;
typedef unsigned short ushort;

__device__ __forceinline__ f4 mfma16(short8 a, short8 b, f4 c) {
    return __builtin_amdgcn_mfma_f32_16x16x32_bf16(a, b, c, 0, 0, 0);
}
__device__ __forceinline__ ushort rne16(float x) {
    union { float f; unsigned u; } a; a.f = x;
    return (ushort)((a.u + 0x7fffu + ((a.u >> 16) & 1u)) >> 16);
}
// x ~= hi + lo: hi = truncate-to-bf16(x), lo = rne-bf16(x - hi)
__device__ __forceinline__ void split2(float x, ushort& h, ushort& l) {
    union { float f; unsigned u; } a; a.f = x;
    unsigned hu = a.u & 0xffff0000u;
    h = (ushort)(hu >> 16);
    union { unsigned u; float f; } hb; hb.u = hu;
    l = rne16(x - hb.f);
}
__device__ __forceinline__ short8 ld8(const ushort* p) { return *(const short8*)p; }

// async global->LDS, 16B per lane; LDS dest must be wave-uniform base,
// HW writes lane i at base + i*16. Global addr is per-lane.
__device__ __forceinline__ void gll16(const ushort* g, ushort* l) {
    __builtin_amdgcn_global_load_lds((const __attribute__((address_space(1))) void*)g,
                                     (__attribute__((address_space(3))) void*)l, 16, 0, 0);
}

// ---------- fused weight conversion: 4 jobs on grid.y ----------
__global__ __launch_bounds__(256) void wconv(const float* __restrict__ Wq,
                                             const float* __restrict__ Wk,
                                             const float* __restrict__ Wv,
                                             const float* __restrict__ Wo,
                                             ushort* __restrict__ Wqh, ushort* __restrict__ Wql,
                                             ushort* __restrict__ Wkh, ushort* __restrict__ Wkl,
                                             ushort* __restrict__ Wvb, ushort* __restrict__ Wob) {
    int i = (blockIdx.x * 256 + threadIdx.x) * 4;
    int job = blockIdx.y;
    const float* src = job == 0 ? Wq : job == 1 ? Wk : job == 2 ? Wv : Wo;
    float4 w = *(const float4*)&src[i];
    float xs[4] = {w.x, w.y, w.z, w.w};
    if (job < 2) {
        ushort h[4], l[4];
#pragma unroll
        for (int j = 0; j < 4; ++j) split2(xs[j], h[j], l[j]);
        ushort* ph = job ? Wkh : Wqh;
        ushort* pl = job ? Wkl : Wql;
        *(short4*)&ph[i] = make_short4(h[0], h[1], h[2], h[3]);
        *(short4*)&pl[i] = make_short4(l[0], l[1], l[2], l[3]);
    } else {
        ushort* po = job == 2 ? Wvb : Wob;
        *(short4*)&po[i] = make_short4(rne16(xs[0]), rne16(xs[1]), rne16(xs[2]), rne16(xs[3]));
    }
}

// ---------- fused q/k/v projection (grid.z selects), pipelined loads ----------
template <int B>
__device__ __forceinline__ void ld_qk(const float* __restrict__ X, const ushort* __restrict__ Wh,
                                      const ushort* __restrict__ Wl, int m0, int n0, int la, int qd,
                                      int k0, float4 (&xA)[2][2][2], short8 (&wH)[2][4],
                                      short8 (&wL)[2][4]) {
#pragma unroll
    for (int ms = 0; ms < 2; ++ms) {
        const float* ap = &X[(size_t)(m0 + ms * 16 + la) * DIM + k0 + qd * 8];
        xA[B][ms][0] = *(const float4*)ap;
        xA[B][ms][1] = *(const float4*)(ap + 4);
    }
#pragma unroll
    for (int ns = 0; ns < 4; ++ns) {
        size_t wi = (size_t)(n0 + ns * 16 + la) * DIM + k0 + qd * 8;
        wH[B][ns] = ld8(&Wh[wi]);
        wL[B][ns] = ld8(&Wl[wi]);
    }
}

template <int B>
__device__ __forceinline__ void fma_qk(float4 (&xA)[2][2][2], short8 (&wH)[2][4],
                                       short8 (&wL)[2][4], f4 (&acc)[2][4]) {
    short8 ahi[2], alo[2];
#pragma unroll
    for (int ms = 0; ms < 2; ++ms) {
        float xs[8] = {xA[B][ms][0].x, xA[B][ms][0].y, xA[B][ms][0].z, xA[B][ms][0].w,
                       xA[B][ms][1].x, xA[B][ms][1].y, xA[B][ms][1].z, xA[B][ms][1].w};
#pragma unroll
        for (int j = 0; j < 8; ++j) {
            ushort h, l;
            split2(xs[j], h, l);
            ahi[ms][j] = (short)h;
            alo[ms][j] = (short)l;
        }
    }
#pragma unroll
    for (int ns = 0; ns < 4; ++ns)
#pragma unroll
        for (int ms = 0; ms < 2; ++ms) {
            acc[ms][ns] = mfma16(alo[ms], wH[B][ns], acc[ms][ns]);
            acc[ms][ns] = mfma16(ahi[ms], wL[B][ns], acc[ms][ns]);
            acc[ms][ns] = mfma16(ahi[ms], wH[B][ns], acc[ms][ns]);
        }
}

template <int B>
__device__ __forceinline__ void ld_v(const float* __restrict__ X, const ushort* __restrict__ Wb,
                                     int m0, int n0, int la, int qd, int k0,
                                     float4 (&xA)[2][2][2], short8 (&wH)[2][4]) {
#pragma unroll
    for (int ms = 0; ms < 2; ++ms) {
        const float* ap = &X[(size_t)(m0 + ms * 16 + la) * DIM + k0 + qd * 8];
        xA[B][ms][0] = *(const float4*)ap;
        xA[B][ms][1] = *(const float4*)(ap + 4);
    }
#pragma unroll
    for (int ns = 0; ns < 4; ++ns)
        wH[B][ns] = ld8(&Wb[(size_t)(n0 + ns * 16 + la) * DIM + k0 + qd * 8]);
}

template <int B>
__device__ __forceinline__ void fma_v(float4 (&xA)[2][2][2], short8 (&wH)[2][4], f4 (&acc)[2][4]) {
    short8 a[2];
#pragma unroll
    for (int ms = 0; ms < 2; ++ms) {
        float xs[8] = {xA[B][ms][0].x, xA[B][ms][0].y, xA[B][ms][0].z, xA[B][ms][0].w,
                       xA[B][ms][1].x, xA[B][ms][1].y, xA[B][ms][1].z, xA[B][ms][1].w};
#pragma unroll
        for (int j = 0; j < 8; ++j) a[ms][j] = (short)rne16(xs[j]);
    }
#pragma unroll
    for (int ns = 0; ns < 4; ++ns)
#pragma unroll
        for (int ms = 0; ms < 2; ++ms) acc[ms][ns] = mfma16(a[ms], wH[B][ns], acc[ms][ns]);
}

__global__ __launch_bounds__(256, 2) void proj_qkv(
    const float* __restrict__ query, const float* __restrict__ key, const float* __restrict__ value,
    const ushort* __restrict__ Wqh, const ushort* __restrict__ Wql,
    const ushort* __restrict__ Wkh, const ushort* __restrict__ Wkl,
    const ushort* __restrict__ Wvb,
    const float* __restrict__ bq, const float* __restrict__ bk, const float* __restrict__ bv,
    ushort* __restrict__ Qhi, ushort* __restrict__ Qlo,
    ushort* __restrict__ Khi, ushort* __restrict__ Klo, ushort* __restrict__ Vt) {
    const int z = blockIdx.z;
    const int t = threadIdx.x, wave = t >> 6, lane = t & 63;
    const int la = lane & 15, qd = lane >> 4;
    const int m0 = blockIdx.x * 128 + wave * 32;
    const int n0 = blockIdx.y * 64;

    float4 xA[2][2][2];
    short8 wH[2][4], wL[2][4];
    f4 acc[2][4] = {};

    if (z < 2) {
        const float* X = z ? key : query;
        const ushort* Wh = z ? Wkh : Wqh;
        const ushort* Wl = z ? Wkl : Wql;
        ld_qk<0>(X, Wh, Wl, m0, n0, la, qd, 0, xA, wH, wL);
        for (int k0 = 0; k0 < DIM; k0 += 64) {
            ld_qk<1>(X, Wh, Wl, m0, n0, la, qd, k0 + 32, xA, wH, wL);
            fma_qk<0>(xA, wH, wL, acc);
            ld_qk<0>(X, Wh, Wl, m0, n0, la, qd, (k0 + 64) & (DIM - 1), xA, wH, wL);
            fma_qk<1>(xA, wH, wL, acc);
        }
        const float* bias = z ? bk : bq;
        ushort* Oh = z ? Khi : Qhi;
        ushort* Ol = z ? Klo : Qlo;
#pragma unroll
        for (int ns = 0; ns < 4; ++ns) {
            int n = n0 + ns * 16 + la;
            float bvv = bias[n];
            int h = n >> 6, d = n & 63;
#pragma unroll
            for (int ms = 0; ms < 2; ++ms)
#pragma unroll
                for (int r = 0; r < 4; ++r) {
                    int m = m0 + ms * 16 + qd * 4 + r;
                    int b = m >> 11, s = m & 2047;
                    ushort hh, ll;
                    split2(acc[ms][ns][r] + bvv, hh, ll);
                    size_t o = ((size_t)(b * NH + h) * SEQ + s) * HD + d;
                    __builtin_nontemporal_store(hh, &Oh[o]);
                    __builtin_nontemporal_store(ll, &Ol[o]);
                }
        }
    } else {
        __shared__ ushort Ts[4][64][40];  // per-wave private [wave][d][m], 16B-aligned rows
        ld_v<0>(value, Wvb, m0, n0, la, qd, 0, xA, wH);
        for (int k0 = 0; k0 < DIM; k0 += 64) {
            ld_v<1>(value, Wvb, m0, n0, la, qd, k0 + 32, xA, wH);
            fma_v<0>(xA, wH, acc);
            ld_v<0>(value, Wvb, m0, n0, la, qd, (k0 + 64) & (DIM - 1), xA, wH);
            fma_v<1>(xA, wH, acc);
        }
#pragma unroll
        for (int ns = 0; ns < 4; ++ns) {
            float bvv = bv[n0 + ns * 16 + la];
#pragma unroll
            for (int ms = 0; ms < 2; ++ms)
#pragma unroll
                for (int r = 0; r < 4; ++r)
                    Ts[wave][ns * 16 + la][ms * 16 + qd * 4 + r] = rne16(acc[ms][ns][r] + bvv);
        }
        // same-wave LDS round-trip (lgkmcnt-ordered, wave-private region)
        int b = m0 >> 11, s0 = m0 & 2047, h = n0 >> 6;
        size_t vbase = (size_t)(b * NH + h) * HD * SEQ;
#pragma unroll
        for (int it = 0; it < 4; ++it) {
            int d = it * 16 + (lane >> 2), sc = (lane & 3) * 8;
            short8 v0 = *(const short8*)&Ts[wave][d][sc];
            __builtin_nontemporal_store(v0, (short8*)&Vt[vbase + (size_t)d * SEQ + s0 + sc]);
        }
    }
}

// ---------- fused attention: LDS-staged K (dbuf, swizzled), 32-key tiles ----
// Grid 32 (bh) x 32 (q-blocks of 64). 4 waves/block share the K tile.
// LDS: kb[2 buf][2 hi/lo][32 keys][64 hw] = 16 KiB + Ps 5 KiB = 21.25 KiB
// -> 4 blocks/CU.
__global__ __launch_bounds__(256, 4) void attn_mfma(
    const ushort* __restrict__ Qhi, const ushort* __restrict__ Qlo,
    const ushort* __restrict__ Khi, const ushort* __restrict__ Klo,
    const ushort* __restrict__ Vt, float* __restrict__ attn, ushort* __restrict__ ctxb) {
    __shared__ ushort kb[2][2][32][64];  // [buf][hl][key][halfword], chunk-swizzled content
    __shared__ ushort Ps[64][40];        // 4 waves x 16 wave-private rows
    const int t = threadIdx.x, wave = t >> 6, lane = t & 63;
    const int la = lane & 15, qd = lane >> 4;
    const int bh = blockIdx.x;
    const int q0 = blockIdx.y * 64 + wave * 16;

    short8 qhi[2], qlo[2];
#pragma unroll
    for (int ks = 0; ks < 2; ++ks) {
        size_t qi = ((size_t)bh * SEQ + q0 + la) * HD + ks * 32 + qd * 8;
        qhi[ks] = ld8(&Qhi[qi]);
        qlo[ks] = ld8(&Qlo[qi]);
    }

    // staging geometry: wave w stages keys [w*8, w*8+8); lane l -> key w*8+(l>>3),
    // LDS chunk (l&7). LDS slot [key][j] holds GLOBAL chunk j^(key&7) (involution),
    // so the read side applies the same XOR and gets linear data. 8 lanes per key
    // still cover one full 128B row of K -> coalesced.
    const int skey = wave * 8 + (lane >> 3);            // key within tile
    const int schunk = (lane & 7) ^ (lane >> 3);        // pre-swizzled source chunk
    const size_t sgbase = ((size_t)bh * SEQ + skey) * HD + schunk * 8;

    // prologue: stage tile 0 into buf 0
    gll16(&Khi[sgbase], &kb[0][0][wave * 8][0]);
    gll16(&Klo[sgbase], &kb[0][1][wave * 8][0]);
    __syncthreads();

    f4 cacc[4] = {};
    for (int h = 0; h < 64; ++h) {
        const int c0 = h * 32;
        const int cur = h & 1;

        // V loads first (register path, L2-resident) so the compiler's V-wait
        // does not drain the stage loads issued below.
        short8 vB[4];
#pragma unroll
        for (int ns = 0; ns < 4; ++ns)
            vB[ns] = ld8(&Vt[((size_t)bh * HD + ns * 16 + la) * SEQ + c0 + qd * 8]);

        // async-stage tile h+1 into the other buffer (released by the barrier
        // at the end of iteration h-1; nobody reads it during iteration h).
        if (h + 1 < 64) {
            gll16(&Khi[sgbase + (size_t)(c0 + 32) * HD], &kb[cur ^ 1][0][wave * 8][0]);
            gll16(&Klo[sgbase + (size_t)(c0 + 32) * HD], &kb[cur ^ 1][1][wave * 8][0]);
        }

        // K fragments from LDS (swizzled read; same bf16 words as the old
        // direct global loads -> bit-identical MFMA inputs)
        short8 kH[2][2], kL[2][2];
#pragma unroll
        for (int n2 = 0; n2 < 2; ++n2)
#pragma unroll
            for (int ks = 0; ks < 2; ++ks) {
                int row = n2 * 16 + la;
                int sw = ((ks * 4 + qd) ^ (la & 7)) * 8;  // halfword offset in row
                kH[n2][ks] = *(const short8*)&kb[cur][0][row][sw];
                kL[n2][ks] = *(const short8*)&kb[cur][1][row][sw];
            }

        // QK^T, 3-pass hi/lo chain — per-element op order identical to r5/r7
        f4 s[2] = {};
        __builtin_amdgcn_s_setprio(1);
#pragma unroll
        for (int n2 = 0; n2 < 2; ++n2)
#pragma unroll
            for (int ks = 0; ks < 2; ++ks) {
                s[n2] = mfma16(qlo[ks], kH[n2][ks], s[n2]);
                s[n2] = mfma16(qhi[ks], kL[n2][ks], s[n2]);
                s[n2] = mfma16(qhi[ks], kH[n2][ks], s[n2]);
            }
        __builtin_amdgcn_s_setprio(0);

        // spike -> Ps (wave-private rows)
#pragma unroll
        for (int n2 = 0; n2 < 2; ++n2)
#pragma unroll
            for (int r = 0; r < 4; ++r)
                Ps[wave * 16 + qd * 4 + r][n2 * 16 + la] =
                    s[n2][r] > 0.f ? (ushort)0x3f80 : (ushort)0;

        // attn tile: Ps readback -> widen -> coalesced float4 nt stores
#pragma unroll
        for (int it = 0; it < 2; ++it) {
            int row = it * 8 + (lane >> 3);
            short4 p = *(const short4*)&Ps[wave * 16 + row][(lane & 7) * 4];
            f4 o;
            o.x = __uint_as_float(((unsigned)(ushort)p.x) << 16);
            o.y = __uint_as_float(((unsigned)(ushort)p.y) << 16);
            o.z = __uint_as_float(((unsigned)(ushort)p.z) << 16);
            o.w = __uint_as_float(((unsigned)(ushort)p.w) << 16);
            __builtin_nontemporal_store(
                o, (f4*)&attn[((size_t)bh * SEQ + q0 + row) * SEQ + c0 + (lane & 7) * 4]);
        }

        // ctx += P @ V over this 32-key tile
        short8 pa = *(const short8*)&Ps[wave * 16 + la][qd * 8];
        __builtin_amdgcn_s_setprio(1);
#pragma unroll
        for (int ns = 0; ns < 4; ++ns) cacc[ns] = mfma16(pa, vB[ns], cacc[ns]);
        __builtin_amdgcn_s_setprio(0);

        // release kb[cur] for restaging; guarantees stage of tile h+1 landed
        // (syncthreads drains vmcnt+lgkmcnt before the barrier).
        __syncthreads();
    }
#pragma unroll
    for (int ns = 0; ns < 4; ++ns)
#pragma unroll
        for (int r = 0; r < 4; ++r) {
            int qrow = q0 + qd * 4 + r;
            __builtin_nontemporal_store(rne16(cacc[ns][r]),
                                        &ctxb[((size_t)bh * SEQ + qrow) * HD + ns * 16 + la]);
        }
}

// ---------- out projection, pipelined ----------
template <int B>
__device__ __forceinline__ void ld_o(const ushort* __restrict__ Ctx, const ushort* __restrict__ Wb,
                                     int m0, int n0, int la, int qd, int k0,
                                     short8 (&aO)[2][2], short8 (&wO)[2][4]) {
#pragma unroll
    for (int ms = 0; ms < 2; ++ms) {
        int m = m0 + ms * 16 + la;
        int b = m >> 11, s = m & 2047;
        int k = k0 + qd * 8;
        int h = k >> 6, d = k & 63;
        aO[B][ms] = ld8(&Ctx[((size_t)(b * NH + h) * SEQ + s) * HD + d]);
    }
#pragma unroll
    for (int ns = 0; ns < 4; ++ns)
        wO[B][ns] = ld8(&Wb[(size_t)(n0 + ns * 16 + la) * DIM + k0 + qd * 8]);
}

__global__ __launch_bounds__(256, 2) void proj_out(const ushort* __restrict__ Ctx,
                                                   const ushort* __restrict__ Wb,
                                                   const float* __restrict__ bias,
                                                   float* __restrict__ out) {
    const int t = threadIdx.x, wave = t >> 6, lane = t & 63;
    const int la = lane & 15, qd = lane >> 4;
    const int m0 = blockIdx.x * 128 + wave * 32;
    const int n0 = blockIdx.y * 64;

    short8 aO[2][2], wO[2][4];
    f4 acc[2][4] = {};
    ld_o<0>(Ctx, Wb, m0, n0, la, qd, 0, aO, wO);
    for (int k0 = 0; k0 < DIM; k0 += 64) {
        ld_o<1>(Ctx, Wb, m0, n0, la, qd, k0 + 32, aO, wO);
#pragma unroll
        for (int ns = 0; ns < 4; ++ns)
#pragma unroll
            for (int ms = 0; ms < 2; ++ms) acc[ms][ns] = mfma16(aO[0][ms], wO[0][ns], acc[ms][ns]);
        ld_o<0>(Ctx, Wb, m0, n0, la, qd, (k0 + 64) & (DIM - 1), aO, wO);
#pragma unroll
        for (int ns = 0; ns < 4; ++ns)
#pragma unroll
            for (int ms = 0; ms < 2; ++ms) acc[ms][ns] = mfma16(aO[1][ms], wO[1][ns], acc[ms][ns]);
    }
#pragma unroll
    for (int ns = 0; ns < 4; ++ns) {
        int n = n0 + ns * 16 + la;
        float bvv = bias[n];
#pragma unroll
        for (int ms = 0; ms < 2; ++ms)
#pragma unroll
            for (int r = 0; r < 4; ++r) {
                int m = m0 + ms * 16 + qd * 4 + r;
                __builtin_nontemporal_store(acc[ms][ns][r] + bvv, &out[(size_t)m * DIM + n]);
            }
    }
}

extern "C" void kernel_launch(void* const* d_in, const int* in_sizes, int n_in,
                              void* d_out, int out_size, void* d_ws, size_t ws_size,
                              hipStream_t stream) {
    const float* query = (const float*)d_in[0];
    const float* key   = (const float*)d_in[1];
    const float* value = (const float*)d_in[2];
    const float* Wq = (const float*)d_in[3];
    const float* bq = (const float*)d_in[4];
    const float* Wk = (const float*)d_in[5];
    const float* bk = (const float*)d_in[6];
    const float* Wv = (const float*)d_in[7];
    const float* bv = (const float*)d_in[8];
    const float* Wo = (const float*)d_in[9];
    const float* bo = (const float*)d_in[10];

    float* out  = (float*)d_out;
    float* attn = out + (size_t)MROWS * DIM;

    const size_t NE = (size_t)MROWS * DIM;  // 4,194,304
    const size_t WE = (size_t)DIM * DIM;    // 1,048,576
    ushort* Qhi = (ushort*)d_ws;            // 5 x NE = 40 MiB
    ushort* Qlo = Qhi + NE;
    ushort* Khi = Qlo + NE;
    ushort* Klo = Khi + NE;
    ushort* Vt  = Klo + NE;
    ushort* Wqh = Vt + NE;                  // 6 x WE = 12 MiB
    ushort* Wql = Wqh + WE;
    ushort* Wkh = Wql + WE;
    ushort* Wkl = Wkh + WE;
    ushort* Wvb = Wkl + WE;
    ushort* Wob = Wvb + WE;
    ushort* Ctx = Wqh;                      // overlays Wqh..Wkl (dead after proj_qkv)

    dim3 blk(256);
    hipLaunchKernelGGL(wconv, dim3(WE / 1024, 4), blk, 0, stream,
                       Wq, Wk, Wv, Wo, Wqh, Wql, Wkh, Wkl, Wvb, Wob);
    hipLaunchKernelGGL(proj_qkv, dim3(32, 16, 3), blk, 0, stream,
                       query, key, value, Wqh, Wql, Wkh, Wkl, Wvb, bq, bk, bv,
                       Qhi, Qlo, Khi, Klo, Vt);
    hipLaunchKernelGGL(attn_mfma, dim3(32, 32), blk, 0, stream,
                       Qhi, Qlo, Khi, Klo, Vt, attn, Ctx);
    hipLaunchKernelGGL(proj_out, dim3(32, 16), blk, 0, stream, Ctx, Wob, bo, out);
}